// Round 3
// baseline (346.985 us; speedup 1.0000x reference)
//
#include <hip/hip_runtime.h>

typedef __bf16 bf16x8 __attribute__((ext_vector_type(8)));
typedef float f32x4 __attribute__((ext_vector_type(4)));

__device__ __forceinline__ unsigned short f2bf(float f) {
    union { float f; unsigned int u; } v; v.f = f;
    unsigned int u = v.u;
    unsigned int r = (u + 0x7fffu + ((u >> 16) & 1u)) >> 16;
    return (unsigned short)r;
}

// ---------------------------------------------------------------------------
// Kernel 1: reconstruct TT conv weights -> bf16, MFMA-A-fragment layout.
// kidx = (kh*3+kw)*128 + c ; stored wb[(kidx>>3)*2048 + d*8 + (kidx&7)]
// ---------------------------------------------------------------------------
__global__ void build_w_kernel(const float* __restrict__ core0,
                               const float* __restrict__ core1,
                               const float* __restrict__ core2,
                               unsigned short* __restrict__ wb) {
    __shared__ float s1[96];   // core1[d]: [r][kh][s]
    __shared__ float s2[12];   // core2[d]: [s][kw]
    const int d = blockIdx.x;
    const int c = threadIdx.x;   // 128 threads
    if (c < 96) s1[c] = core1[d * 96 + c];
    if (c >= 96 && c < 108) s2[c - 96] = core2[d * 12 + (c - 96)];
    __syncthreads();
    float t0[8];
#pragma unroll
    for (int r = 0; r < 8; ++r) t0[r] = core0[(d * 128 + c) * 8 + r];
#pragma unroll
    for (int kh = 0; kh < 3; ++kh) {
        float v[4] = {0.f, 0.f, 0.f, 0.f};
#pragma unroll
        for (int r = 0; r < 8; ++r)
#pragma unroll
            for (int s = 0; s < 4; ++s)
                v[s] += t0[r] * s1[(r * 3 + kh) * 4 + s];
#pragma unroll
        for (int kw = 0; kw < 3; ++kw) {
            float val = 0.f;
#pragma unroll
            for (int s = 0; s < 4; ++s) val += v[s] * s2[s * 3 + kw];
            const int kidx = (kh * 3 + kw) * 128 + c;
            wb[(kidx >> 3) * 2048 + d * 8 + (kidx & 7)] = f2bf(val);
        }
    }
}

// ---------------------------------------------------------------------------
// Kernel 2: implicit-GEMM conv, 4-row strips with rolling LDS window.
// Grid = 512 blocks (32 n x 16 strips) = exactly 2 blocks/CU, one round.
// Per block: stage image rows h0-1..h0+2 into 4 LDS slots (slot(r)=(r+1)&3),
// pass 0 computes output rows h0,h0+1 while rows h0+3,h0+4 are prefetched
// into registers; rotate slots between passes; pass 1 computes h0+2,h0+3.
// Per chunk per wave: 4 A-frag global loads (L2-resident), 8 ds_read_b128,
// 32 MFMA 16x16x32. 3 barriers per block total.
// ---------------------------------------------------------------------------
#define LC   136          // padded c dim (128+8)
#define SLOT (66 * LC)    // one row-slot in ushorts

__device__ __forceinline__ void load_row_unit(const float* __restrict__ x,
                                              int n, int rimg, int tid, int u,
                                              float4 p[4]) {
    const int it = tid + (u << 8);
    const int w4 = it & 15;
    const int cg = it >> 4;          // 0..31 across u=0,1
    p[0] = p[1] = p[2] = p[3] = make_float4(0.f, 0.f, 0.f, 0.f);
    if (rimg >= 0 && rimg < 64) {
        const float4* gp = (const float4*)(x + (((n * 128 + (cg << 2)) * 64 + rimg) << 6) + (w4 << 2));
        p[0] = gp[0];
        p[1] = gp[1024];   // +1 c-plane
        p[2] = gp[2048];
        p[3] = gp[3072];
    }
}

__device__ __forceinline__ void write_row_unit(unsigned short* xl, int slot,
                                               int tid, int u, const float4 p[4]) {
    const int it = tid + (u << 8);
    const int w4 = it & 15;
    const int cg = it >> 4;
    unsigned short* base = xl + slot * SLOT + ((w4 << 2) + 1) * LC + (cg << 2);
    *(ushort4*)(base)          = make_ushort4(f2bf(p[0].x), f2bf(p[1].x), f2bf(p[2].x), f2bf(p[3].x));
    *(ushort4*)(base + LC)     = make_ushort4(f2bf(p[0].y), f2bf(p[1].y), f2bf(p[2].y), f2bf(p[3].y));
    *(ushort4*)(base + 2 * LC) = make_ushort4(f2bf(p[0].z), f2bf(p[1].z), f2bf(p[2].z), f2bf(p[3].z));
    *(ushort4*)(base + 3 * LC) = make_ushort4(f2bf(p[0].w), f2bf(p[1].w), f2bf(p[2].w), f2bf(p[3].w));
}

__device__ __forceinline__ void kloop_pass(const bf16x8* __restrict__ wgv,
                                           const unsigned short* __restrict__ xl,
                                           int hb,   // 0 (pass 0) or 2 (pass 1), literal
                                           int abase, int l15, int quad,
                                           f32x4 acc[4][8]) {
    bf16x8 an[4];
#pragma unroll
    for (int dt = 0; dt < 4; ++dt) an[dt] = wgv[abase + dt * 16];
#pragma unroll
    for (int tap = 0; tap < 9; ++tap) {
        const int kh = tap / 3;
        const int kw = tap - kh * 3;
        const int sA = (hb + kh) & 3;          // image row hA-1+kh
        const int sB = (hb + kh + 1) & 3;      // image row hA+kh
        const unsigned short* baseA = xl + sA * SLOT + (l15 + kw) * LC + quad * 8;
        const unsigned short* baseB = xl + sB * SLOT + (l15 + kw) * LC + quad * 8;
#pragma unroll
        for (int c4 = 0; c4 < 4; ++c4) {
            const int ch = tap * 4 + c4;
            bf16x8 ac[4];
#pragma unroll
            for (int dt = 0; dt < 4; ++dt) ac[dt] = an[dt];
            if (ch + 1 < 36) {
                const bf16x8* g2 = wgv + (ch + 1) * 1024 + abase;
#pragma unroll
                for (int dt = 0; dt < 4; ++dt) an[dt] = g2[dt * 16];
            }
            const int c0 = c4 << 5;
            bf16x8 b0[4];
#pragma unroll
            for (int pt = 0; pt < 4; ++pt) b0[pt] = *(const bf16x8*)(baseA + pt * 16 * LC + c0);
#pragma unroll
            for (int dt = 0; dt < 4; ++dt)
#pragma unroll
                for (int pt = 0; pt < 4; ++pt)
                    acc[dt][pt] = __builtin_amdgcn_mfma_f32_16x16x32_bf16(
                        ac[dt], b0[pt], acc[dt][pt], 0, 0, 0);
            bf16x8 b1[4];
#pragma unroll
            for (int pt = 0; pt < 4; ++pt) b1[pt] = *(const bf16x8*)(baseB + pt * 16 * LC + c0);
#pragma unroll
            for (int dt = 0; dt < 4; ++dt)
#pragma unroll
                for (int pt = 0; pt < 4; ++pt)
                    acc[dt][4 + pt] = __builtin_amdgcn_mfma_f32_16x16x32_bf16(
                        ac[dt], b1[pt], acc[dt][4 + pt], 0, 0, 0);
        }
    }
}

__device__ __forceinline__ void epilogue(float* __restrict__ out, const f32x4 acc[4][8],
                                         int n, int hA, int dwave, int quad, int l15,
                                         float bv) {
#pragma unroll
    for (int dt = 0; dt < 4; ++dt)
#pragma unroll
        for (int pt = 0; pt < 8; ++pt) {
            const int d  = dwave + dt * 16 + quad * 4;
            const int hh = hA + (pt >> 2);
            const int w  = (pt & 3) * 16 + l15;
            float* op = out + ((n * 256 + d) * 64 + hh) * 64 + w;
#pragma unroll
            for (int r = 0; r < 4; ++r) op[r * 4096] = acc[dt][pt][r] + bv;
        }
}

__global__ __launch_bounds__(256, 2) void conv_mfma_kernel(
    const float* __restrict__ x, const unsigned short* __restrict__ wb,
    const float* __restrict__ bias, float* __restrict__ out) {
    __shared__ __align__(16) unsigned short xl[4 * SLOT];   // 71,808 B

    const int tid  = threadIdx.x;
    const int lane = tid & 63;
    const int wv   = tid >> 6;
    const int l15  = lane & 15;
    const int quad = lane >> 4;
    const int bid  = blockIdx.x;
    const int n    = bid >> 4;
    const int h0   = (bid & 15) << 2;   // h0 ≡ 0 (mod 4) => slot(h0-1+r) = r

    // zero halo columns (wcol 0 and 65) in all 4 slots
    if (tid < 128) {
        const int slot = tid >> 5;
        const int j    = tid & 31;
        const int col  = (j >> 4) ? 65 : 0;
        const int c    = (j & 15) << 3;
        *(uint4*)(xl + slot * SLOT + col * LC + c) = make_uint4(0u, 0u, 0u, 0u);
    }

    // initial stage: image rows h0-1..h0+2 -> slots 0..3
#pragma unroll
    for (int row = 0; row < 4; ++row) {
        const int rimg = h0 - 1 + row;
#pragma unroll
        for (int u = 0; u < 2; ++u) {
            float4 p[4];
            load_row_unit(x, n, rimg, tid, u, p);
            write_row_unit(xl, row, tid, u, p);
        }
    }
    __syncthreads();

    const bf16x8* wgv = (const bf16x8*)wb;
    const int dwave = wv << 6;
    const int abase = quad * 256 + dwave + l15;
    const float bv = bias[0];

    // prefetch image row h0+3 (always in range) into registers
    float4 pfA[2][4];
    load_row_unit(x, n, h0 + 3, tid, 0, pfA[0]);
    load_row_unit(x, n, h0 + 3, tid, 1, pfA[1]);

    f32x4 acc[4][8];
#pragma unroll
    for (int a0 = 0; a0 < 4; ++a0)
#pragma unroll
        for (int b0 = 0; b0 < 8; ++b0) acc[a0][b0] = (f32x4){0.f, 0.f, 0.f, 0.f};

    kloop_pass(wgv, xl, 0, abase, l15, quad, acc);   // output rows h0, h0+1

    // prefetch image row h0+4 (OOB -> zeros when h0 == 60)
    float4 pfB[2][4];
    load_row_unit(x, n, h0 + 4, tid, 0, pfB[0]);
    load_row_unit(x, n, h0 + 4, tid, 1, pfB[1]);

    __syncthreads();   // all pass-0 LDS reads done
    // rotate window: row h0+3 -> slot 0, row h0+4 -> slot 1
    write_row_unit(xl, 0, tid, 0, pfA[0]);
    write_row_unit(xl, 0, tid, 1, pfA[1]);
    write_row_unit(xl, 1, tid, 0, pfB[0]);
    write_row_unit(xl, 1, tid, 1, pfB[1]);
    __syncthreads();

    // pass-0 epilogue AFTER the barrier: store drain overlaps pass-1 compute
    epilogue(out, acc, n, h0, dwave, quad, l15, bv);

#pragma unroll
    for (int a0 = 0; a0 < 4; ++a0)
#pragma unroll
        for (int b0 = 0; b0 < 8; ++b0) acc[a0][b0] = (f32x4){0.f, 0.f, 0.f, 0.f};

    kloop_pass(wgv, xl, 2, abase, l15, quad, acc);   // output rows h0+2, h0+3
    epilogue(out, acc, n, h0 + 2, dwave, quad, l15, bv);
}

extern "C" void kernel_launch(void* const* d_in, const int* in_sizes, int n_in,
                              void* d_out, int out_size, void* d_ws, size_t ws_size,
                              hipStream_t stream) {
    const float* x     = (const float*)d_in[0];
    const float* core0 = (const float*)d_in[1];
    const float* core1 = (const float*)d_in[2];
    const float* core2 = (const float*)d_in[3];
    const float* bias  = (const float*)d_in[4];
    unsigned short* wb = (unsigned short*)d_ws;   // 1152*256*2 = 589,824 B

    build_w_kernel<<<256, 128, 0, stream>>>(core0, core1, core2, wb);
    conv_mfma_kernel<<<512, 256, 0, stream>>>(x, wb, bias, (float*)d_out);
}